// Round 3
// baseline (512.811 us; speedup 1.0000x reference)
//
#include <hip/hip_runtime.h>
#include <math.h>

// Problem constants (from reference): x shape (5, 512, 128, 256) fp32.
#define KMAX   5        // max_cav
#define NC     512      // FEATURE_DIM
#define HW     32768    // 128*256 spatial positions
#define HW4    (HW / 4)
#define NCHUNK 32       // c-chunks for partial-dot kernel
#define CPC    (NC / NCHUNK)   // 16 channels per chunk
#define CG     8        // c's per thread in K3
#define INV_SQRT_DIM 0.044194173824159216f  // 1/sqrt(512)

typedef float vfloat4 __attribute__((ext_vector_type(4)));

__device__ __forceinline__ int clamp_K(const int* __restrict__ rlp) {
    int K = *rlp;                 // wave-uniform scalar load (L2-cached)
    return K < 0 ? 0 : (K > KMAX ? KMAX : K);
}

// ---------------------------------------------------------------------------
// K1: partial dots over a c-chunk; 2 float4 b-positions per thread for ILP.
// grid = (HW4/512, NCHUNK) = (16, 32), block = 256.
// partial layout: partial[(chunk*KMAX + k)*HW + b]
// ---------------------------------------------------------------------------
template <int K>
__device__ __forceinline__ void k1_body(const vfloat4* __restrict__ xv,
                                        vfloat4* __restrict__ pv,
                                        int b4, int chunk) {
    vfloat4 da[K], db[K];
#pragma unroll
    for (int k = 0; k < K; ++k) { da[k] = (vfloat4)0.f; db[k] = (vfloat4)0.f; }

    const int c0 = chunk * CPC;
#pragma unroll 2
    for (int i = 0; i < CPC; ++i) {
        const int c = c0 + i;
        const vfloat4 x0a = xv[(size_t)c * HW4 + b4];
        const vfloat4 x0b = xv[(size_t)c * HW4 + b4 + 256];
        da[0] += x0a * x0a;  db[0] += x0b * x0b;
#pragma unroll
        for (int k = 1; k < K; ++k) {
            const vfloat4 xka = xv[((size_t)k * NC + c) * HW4 + b4];
            const vfloat4 xkb = xv[((size_t)k * NC + c) * HW4 + b4 + 256];
            da[k] += x0a * xka;  db[k] += x0b * xkb;
        }
    }
#pragma unroll
    for (int k = 0; k < K; ++k) {
        pv[((size_t)chunk * KMAX + k) * HW4 + b4]       = da[k];
        pv[((size_t)chunk * KMAX + k) * HW4 + b4 + 256] = db[k];
    }
}

__global__ void k1_partial_dots(const float* __restrict__ x,
                                const int* __restrict__ rlp,
                                float* __restrict__ partial) {
    const int b4    = blockIdx.x * 512 + threadIdx.x;   // first of two float4s
    const int chunk = blockIdx.y;
    const int K     = clamp_K(rlp);
    const vfloat4* xv = (const vfloat4*)x;
    vfloat4*       pv = (vfloat4*)partial;
    switch (K) {                       // wave-uniform branch
        case 1: k1_body<1>(xv, pv, b4, chunk); break;
        case 2: k1_body<2>(xv, pv, b4, chunk); break;
        case 3: k1_body<3>(xv, pv, b4, chunk); break;
        case 4: k1_body<4>(xv, pv, b4, chunk); break;
        case 5: k1_body<5>(xv, pv, b4, chunk); break;
        default: break;                // K==0: nothing to write
    }
}

// ---------------------------------------------------------------------------
// K2: reduce chunk partials, masked softmax over k, write attn[k*HW + b].
// grid = HW/256 = 128, block = 256.
// ---------------------------------------------------------------------------
template <int K>
__device__ __forceinline__ void k2_body(const float* __restrict__ partial,
                                        float* __restrict__ attn, int b) {
    float d[K];
#pragma unroll
    for (int k = 0; k < K; ++k) d[k] = 0.f;
#pragma unroll
    for (int ch = 0; ch < NCHUNK; ++ch) {
#pragma unroll
        for (int k = 0; k < K; ++k)
            d[k] += __builtin_nontemporal_load(&partial[((size_t)ch * KMAX + k) * HW + b]);
    }
    float m = -INFINITY;
#pragma unroll
    for (int k = 0; k < K; ++k) { d[k] *= INV_SQRT_DIM; m = fmaxf(m, d[k]); }
    float s = 0.f;
#pragma unroll
    for (int k = 0; k < K; ++k) { d[k] = expf(d[k] - m); s += d[k]; }
    const float inv = 1.f / s;
#pragma unroll
    for (int k = 0; k < KMAX; ++k)
        attn[(size_t)k * HW + b] = (k < K) ? d[k] * inv : 0.f;
}

__global__ void k2_softmax(const float* __restrict__ partial,
                           const int* __restrict__ rlp,
                           float* __restrict__ attn) {
    const int b = blockIdx.x * blockDim.x + threadIdx.x;  // 0..HW-1
    const int K = clamp_K(rlp);
    switch (K) {
        case 1: k2_body<1>(partial, attn, b); break;
        case 2: k2_body<2>(partial, attn, b); break;
        case 3: k2_body<3>(partial, attn, b); break;
        case 4: k2_body<4>(partial, attn, b); break;
        case 5: k2_body<5>(partial, attn, b); break;
        default:                                // K==0 -> nan_to_num -> 0
#pragma unroll
            for (int k = 0; k < KMAX; ++k) attn[(size_t)k * HW + b] = 0.f;
            break;
    }
}

// ---------------------------------------------------------------------------
// K3: out[c,b] = sum_k attn[k,b] * x[k,c,b].
// Thread keeps attn for its b4 in registers and loops over CG=8 c's:
// 32 in-flight NT x-loads, NT stores (out never re-read; keep x in L3).
// grid = (HW4/256, NC/CG) = (32, 64), block = 256.
// ---------------------------------------------------------------------------
template <int K>
__device__ __forceinline__ void k3_body(const vfloat4* __restrict__ xv,
                                        const vfloat4* __restrict__ av,
                                        vfloat4* __restrict__ outv,
                                        int b4, int c0) {
    vfloat4 a[K];
#pragma unroll
    for (int k = 0; k < K; ++k) a[k] = av[(size_t)k * HW4 + b4];

#pragma unroll 4
    for (int j = 0; j < CG; ++j) {
        const int c = c0 + j;
        vfloat4 acc = (vfloat4)0.f;
#pragma unroll
        for (int k = 0; k < K; ++k) {
            const vfloat4 xk =
                __builtin_nontemporal_load(&xv[((size_t)k * NC + c) * HW4 + b4]);
            acc += a[k] * xk;
        }
        __builtin_nontemporal_store(acc, &outv[(size_t)c * HW4 + b4]);
    }
}

__global__ void k3_out(const float* __restrict__ x,
                       const int* __restrict__ rlp,
                       const float* __restrict__ attn,
                       float* __restrict__ out) {
    const int b4 = blockIdx.x * blockDim.x + threadIdx.x;  // 0..HW4-1
    const int c0 = blockIdx.y * CG;
    const int K  = clamp_K(rlp);
    const vfloat4* xv   = (const vfloat4*)x;
    const vfloat4* av   = (const vfloat4*)attn;
    vfloat4*       outv = (vfloat4*)out;
    switch (K) {
        case 1: k3_body<1>(xv, av, outv, b4, c0); break;
        case 2: k3_body<2>(xv, av, outv, b4, c0); break;
        case 3: k3_body<3>(xv, av, outv, b4, c0); break;
        case 4: k3_body<4>(xv, av, outv, b4, c0); break;
        case 5: k3_body<5>(xv, av, outv, b4, c0); break;
        default:
#pragma unroll
            for (int j = 0; j < CG; ++j)
                __builtin_nontemporal_store((vfloat4)0.f,
                                            &outv[(size_t)(c0 + j) * HW4 + b4]);
            break;
    }
}

// ---------------------------------------------------------------------------
// Fallback (tiny ws): full dots + softmax in one kernel, writes attn only.
// grid = HW4/256 = 32, block = 256. Slow but only needs 640 KB of ws.
// ---------------------------------------------------------------------------
__global__ void k1_full_softmax(const float* __restrict__ x,
                                const int* __restrict__ rlp,
                                float* __restrict__ attn) {
    const int b4 = blockIdx.x * blockDim.x + threadIdx.x;
    const int K  = clamp_K(rlp);
    const vfloat4* xv = (const vfloat4*)x;

    vfloat4 d[KMAX];
#pragma unroll
    for (int k = 0; k < KMAX; ++k) d[k] = (vfloat4)0.f;

#pragma unroll 4
    for (int c = 0; c < NC; ++c) {
        const vfloat4 x0 = xv[(size_t)c * HW4 + b4];
        d[0] += x0 * x0;
#pragma unroll
        for (int k = 1; k < KMAX; ++k) {
            if (k < K) {
                const vfloat4 xk = xv[((size_t)k * NC + c) * HW4 + b4];
                d[k] += x0 * xk;
            }
        }
    }

    vfloat4 m = (vfloat4)(-INFINITY);
#pragma unroll
    for (int k = 0; k < KMAX; ++k)
        if (k < K) {
            d[k] *= INV_SQRT_DIM;
            m.x = fmaxf(m.x, d[k].x); m.y = fmaxf(m.y, d[k].y);
            m.z = fmaxf(m.z, d[k].z); m.w = fmaxf(m.w, d[k].w);
        }
    vfloat4 s = (vfloat4)0.f;
#pragma unroll
    for (int k = 0; k < KMAX; ++k)
        if (k < K) {
            d[k].x = expf(d[k].x - m.x); d[k].y = expf(d[k].y - m.y);
            d[k].z = expf(d[k].z - m.z); d[k].w = expf(d[k].w - m.w);
            s += d[k];
        }
    vfloat4 inv = (vfloat4)0.f;
    if (K > 0) { inv.x = 1.f / s.x; inv.y = 1.f / s.y; inv.z = 1.f / s.z; inv.w = 1.f / s.w; }

    vfloat4* av = (vfloat4*)attn;
#pragma unroll
    for (int k = 0; k < KMAX; ++k)
        av[(size_t)k * HW4 + b4] = (k < K) ? d[k] * inv : (vfloat4)0.f;
}

extern "C" void kernel_launch(void* const* d_in, const int* in_sizes, int n_in,
                              void* d_out, int out_size, void* d_ws, size_t ws_size,
                              hipStream_t stream) {
    const float* x   = (const float*)d_in[0];
    const int*   rl  = (const int*)d_in[1];
    float*       out = (float*)d_out;
    float*       ws  = (float*)d_ws;

    const size_t partial_elems = (size_t)NCHUNK * KMAX * HW;  // 5.24M floats (21 MB)
    const size_t attn_elems    = (size_t)KMAX * HW;           // 164K floats (640 KB)

    if (ws_size >= (partial_elems + attn_elems) * sizeof(float)) {
        float* partial = ws;
        float* attn    = ws + partial_elems;
        k1_partial_dots<<<dim3(HW4 / 512, NCHUNK), 256, 0, stream>>>(x, rl, partial);
        k2_softmax<<<HW / 256, 256, 0, stream>>>(partial, rl, attn);
        k3_out<<<dim3(HW4 / 256, NC / CG), 256, 0, stream>>>(x, rl, attn, out);
    } else {
        // Fallback: only needs 640 KB of ws.
        float* attn = ws;
        k1_full_softmax<<<HW4 / 256, 256, 0, stream>>>(x, rl, attn);
        k3_out<<<dim3(HW4 / 256, NC / CG), 256, 0, stream>>>(x, rl, attn, out);
    }
}